// Round 19
// baseline (647.059 us; speedup 1.0000x reference)
//
#include <hip/hip_runtime.h>

// ---------------- problem constants (fixed by reference) ----------------
#define N0c 128000
#define N1c 256000
#define N2c 128000
#define BG  64        // graphs per batch
#define KNc 30
#define KEc 60
#define KTc 30
#define COC 16        // conv out channels
#define MLP_IN 1920   // 16*(30+60+30)
#define MLP_H 128
#define KSLICE 8      // MLP stage-1 k-split
#define KCH (MLP_IN / KSLICE)   // 240

#define BINSHIFT 10           // 1024 rows per bin
#define BINROWS  1024
#define BDEPTH   8            // LDS staging depth per bin (epb=nbins*4 -> lambda=4)
#define BSTRIDE  9            // padded stride (keeps r16 bank fix), LDS 20.4KB -> 7 blk/CU
#define BCAP     12288        // max entries per (matrix,bin) in bin_build
#define CANDMAX  256          // topk radix-select candidate cap

typedef unsigned long long u64;
typedef unsigned int u32;

// 60-bit packed tmp entry: val[63:32] | col[27:10] (18b) | rowlo[9:0]
// pairs entry (spmm input): val[63:32] | col[31:0]

struct Mat {
    const int* r; const int* c; const float* v;
    int nnz, nbins, epb, slot, tin, tout;
};
struct Mats { Mat m[7]; int count; };
struct Lifts {
    const float* X[3]; const float* W[3]; float* Y[3];
    int N[3]; int count;
};

// ---------------------------------------------------------------------------
// K1g: batched fused polynomial lift + dense GEMM (grid.y = lift index)
// ---------------------------------------------------------------------------
__global__ __launch_bounds__(256) void gemm_lift_g(Lifts ld)
{
    const int j = blockIdx.y;          // uniform -> scalar selects
    if (j >= ld.count) return;
    const float* __restrict__ X = ld.X[j];
    const float* __restrict__ W = ld.W[j];
    float* __restrict__ Y = ld.Y[j];
    const int N = ld.N[j];

    __shared__ float lw[2048];            // [64][32]
    const int tid = threadIdx.x;
    for (int i = tid; i < 2048; i += 256) lw[i] = W[i];
    __syncthreads();

    const int row = blockIdx.x * 256 + tid;
    if (row >= N) return;

    float x[64];
    const float4* p = reinterpret_cast<const float4*>(X + (size_t)row * 32);
    #pragma unroll
    for (int q = 0; q < 8; ++q) {
        float4 v = p[q];
        x[q*4+0] = v.x; x[q*4+1] = v.y; x[q*4+2] = v.z; x[q*4+3] = v.w;
    }
    #pragma unroll
    for (int i = 0; i < 32; ++i) x[32+i] = x[i] * x[i];

    const float4* lw4 = reinterpret_cast<const float4*>(lw);
    float4* yo = reinterpret_cast<float4*>(Y + (size_t)row * 32);
    #pragma unroll
    for (int j4 = 0; j4 < 8; ++j4) {
        float4 s = {0.f, 0.f, 0.f, 0.f};
        #pragma unroll
        for (int i = 0; i < 64; ++i) {
            float4 wf = lw4[i * 8 + j4];     // broadcast LDS read
            s.x = fmaf(x[i], wf.x, s.x);
            s.y = fmaf(x[i], wf.y, s.y);
            s.z = fmaf(x[i], wf.z, s.z);
            s.w = fmaf(x[i], wf.w, s.w);
        }
        yo[j4] = s;
    }
}

// ---------------------------------------------------------------------------
// B1: batched per-block LDS histogram over bins (grid.y = matrix)
// ---------------------------------------------------------------------------
__global__ __launch_bounds__(256) void bin_hist_g(Mats ms, int* __restrict__ bincnt)
{
    const int j = blockIdx.y;
    if (j >= ms.count) return;
    const Mat mm = ms.m[j];
    const int base = blockIdx.x * mm.epb;
    if (base >= mm.nnz) return;
    int* bc = bincnt + mm.slot * 256;

    __shared__ int lh[256];
    const int tid = threadIdx.x;
    lh[tid] = 0;
    __syncthreads();
    const int cnt = min(mm.epb, mm.nnz - base);
    for (int i = tid; i < cnt; i += 256)
        atomicAdd(&lh[mm.r[base + i] >> BINSHIFT], 1);
    __syncthreads();
    if (tid < mm.nbins && lh[tid]) atomicAdd(&bc[tid], lh[tid]);
}

// ---------------------------------------------------------------------------
// B2: batched LDS-staged binned scatter -> tmpP (60-bit packed).
// Per-thread flush (r11/r12: concurrent per-bin atomics).  BDEPTH=8 with
// epb=nbins*4 (lambda=4, spill ~0.1%) cuts LDS to 20.4KB -> 7 blocks/CU
// (r18: 32% occupancy was the limiter; bank fix alone changed nothing).
// ---------------------------------------------------------------------------
__global__ __launch_bounds__(256) void bin_scatter_g(
    Mats ms, const int* __restrict__ bincnt, int* __restrict__ gcur,
    u64* __restrict__ tmpP)
{
    const int j = blockIdx.y;
    if (j >= ms.count) return;
    const Mat mm = ms.m[j];
    const int blkbase = blockIdx.x * mm.epb;
    if (blkbase >= mm.nnz) return;
    const int* bc = bincnt + mm.slot * 256;
    int* gc = gcur + mm.slot * 256;

    __shared__ u64 bP[256 * BSTRIDE];  // 18.4 KB (padded)
    __shared__ int lc[256];
    __shared__ int smo[256];           // inclusive scan of bincnt slice
    const int tid = threadIdx.x;
    lc[tid] = 0;
    smo[tid] = (tid < mm.nbins) ? bc[tid] : 0;
    __syncthreads();
    for (int off = 1; off < 256; off <<= 1) {
        int t_ = (tid >= off) ? smo[tid - off] : 0;
        __syncthreads();
        smo[tid] += t_;
        __syncthreads();
    }

    const int cnt = min(mm.epb, mm.nnz - blkbase);
    for (int i = tid; i < cnt; i += 256) {
        const int e = blkbase + i;
        const int r = mm.r[e];
        const u64 pv = ((u64)__float_as_uint(mm.v[e]) << 32)
                     | ((u32)mm.c[e] << 10) | (u32)(r & (BINROWS - 1));
        const int b = r >> BINSHIFT;
        const int p = atomicAdd(&lc[b], 1);
        if (p < BDEPTH) {
            bP[b * BSTRIDE + p] = pv;
        } else {                               // rare spill (~0.1%)
            const int off0 = mm.tin + ((b == 0) ? 0 : smo[b - 1]);
            const int g = off0 + atomicAdd(&gc[b], 1);
            tmpP[g] = pv;
        }
    }
    __syncthreads();

    // per-thread flush: thread tid owns bin tid (concurrent atomics)
    if (tid < mm.nbins) {
        int len = lc[tid]; if (len > BDEPTH) len = BDEPTH;
        if (len) {
            const int off0 = mm.tin + ((tid == 0) ? 0 : smo[tid - 1]);
            const int g = off0 + atomicAdd(&gc[tid], len);
            for (int i = 0; i < len; ++i) tmpP[g + i] = bP[tid * BSTRIDE + i];
        }
    }
}

// ---------------------------------------------------------------------------
// B3: batched bin_build: grid (nbins, nmat).  Counting-sort bin entries of
// matrix j into pairs (val<<32|col), emit per-matrix ptr slice (inclusive
// row ends, absolute into pairs).
// ---------------------------------------------------------------------------
__global__ __launch_bounds__(256) void bin_build_g(
    Mats ms, const int* __restrict__ bincnt,
    const u64* __restrict__ tmpP, int R,
    u64* __restrict__ pairs, int* __restrict__ ptrg)
{
    __shared__ unsigned short rl[BCAP];        // 24 KB
    __shared__ int h[BINROWS];                 // 4 KB
    __shared__ int cur[BINROWS];               // 4 KB
    __shared__ int sm[256];
    const int b = blockIdx.x, j = blockIdx.y, tid = threadIdx.x;
    const Mat mm = ms.m[j];
    const int* bc = bincnt + mm.slot * 256;
    int* ptr = ptrg + (size_t)j * R;

    sm[tid] = (tid < mm.nbins) ? bc[tid] : 0;
    __syncthreads();
    for (int off = 1; off < 256; off <<= 1) {
        int t_ = (tid >= off) ? sm[tid - off] : 0;
        __syncthreads();
        sm[tid] += t_;
        __syncthreads();
    }
    const int pre = (b == 0) ? 0 : sm[b - 1];
    const int base_in  = mm.tin  + pre;
    const int base_out = mm.tout + pre;
    int len = sm[b] - pre;
    if (len > BCAP) len = BCAP;                // never expected
    __syncthreads();

    for (int i = tid; i < BINROWS; i += 256) h[i] = 0;
    __syncthreads();
    for (int i = tid; i < len; i += 256) {
        const int r = (int)(tmpP[base_in + i] & (BINROWS - 1));
        rl[i] = (unsigned short)r;
        atomicAdd(&h[r], 1);
    }
    __syncthreads();

    const int i0 = tid * 4;
    const int a0 = h[i0], a1 = h[i0+1], a2 = h[i0+2], a3 = h[i0+3];
    const int s = a0 + a1 + a2 + a3;
    sm[tid] = s;
    __syncthreads();
    for (int off = 1; off < 256; off <<= 1) {
        int t_ = (tid >= off) ? sm[tid - off] : 0;
        __syncthreads();
        sm[tid] += t_;
        __syncthreads();
    }
    const int run = sm[tid] - s;
    cur[i0]   = run;
    cur[i0+1] = run + a0;
    cur[i0+2] = run + a0 + a1;
    cur[i0+3] = run + a0 + a1 + a2;
    const int rstart = b << BINSHIFT;
    if (rstart + i0     < R) ptr[rstart + i0    ] = base_out + run + a0;
    if (rstart + i0 + 1 < R) ptr[rstart + i0 + 1] = base_out + run + a0 + a1;
    if (rstart + i0 + 2 < R) ptr[rstart + i0 + 2] = base_out + run + a0 + a1 + a2;
    if (rstart + i0 + 3 < R) ptr[rstart + i0 + 3] = base_out + run + a0 + a1 + a2 + a3;
    __syncthreads();

    for (int i = tid; i < len; i += 256) {
        const u64 e8 = tmpP[base_in + i];      // L2-hot second read
        const int r = rl[i];
        const int pos = base_out + atomicAdd(&cur[r], 1);
        pairs[pos] = ((e8 >> 32) << 32) | ((e8 >> 10) & 0x3FFFFu);
    }
}

// ---------------------------------------------------------------------------
// K2: grouped CSR gather SPMM: per row, accumulate over NMAT matrices in
// registers; acc written ONCE; sortpool key fused.
// ---------------------------------------------------------------------------
template<int NMAT>
__global__ __launch_bounds__(256) void spmm_group(
    const int* __restrict__ ptrg, int R,
    const u64* __restrict__ pairs,
    int t0, int t1, int t2,
    const float* __restrict__ Y0, const float* __restrict__ Y1,
    const float* __restrict__ Y2,
    float* __restrict__ acc, float* __restrict__ keyout, float kscale)
{
    const int t = blockIdx.x * 256 + threadIdx.x;
    const int row = t >> 3;
    const int l8  = t & 7;
    if (row >= R) return;

    float4 a = {0.f, 0.f, 0.f, 0.f};
    #pragma unroll
    for (int m = 0; m < NMAT; ++m) {
        const int* pm = ptrg + (size_t)m * R;
        const int toff = (m == 0) ? t0 : (m == 1) ? t1 : t2;
        const float4* Y4 = reinterpret_cast<const float4*>(
            (m == 0) ? Y0 : (m == 1) ? Y1 : Y2);
        const int s = (row == 0) ? toff : pm[row - 1];
        const int e = pm[row];
        for (int base = s; base < e; base += 8) {
            int mm = e - base; if (mm > 8) mm = 8;
            u64 pk = (l8 < mm) ? pairs[base + l8] : 0ULL;
            for (int jj = 0; jj < mm; ++jj) {
                const u64 pj = __shfl(pk, jj, 8);
                const int col   = (int)(u32)(pj & 0xffffffffu);
                const float val = __uint_as_float((u32)(pj >> 32));
                const float4 y = Y4[(size_t)col * 8 + l8];
                a.x = fmaf(val, y.x, a.x); a.y = fmaf(val, y.y, a.y);
                a.z = fmaf(val, y.z, a.z); a.w = fmaf(val, y.w, a.w);
            }
        }
    }
    reinterpret_cast<float4*>(acc)[(size_t)row * 8 + l8] = a;
    if (l8 == 7) keyout[row] = kscale * fmaxf(a.w, 0.0f);
}

// ================= tier C fallback: plain lift + atomic COO SPMM ============
__global__ __launch_bounds__(256) void gemm_lift(
    const float* __restrict__ X, int N, const float* __restrict__ W,
    float* __restrict__ Y)
{
    __shared__ float lw[2048];
    const int tid = threadIdx.x;
    for (int i = tid; i < 2048; i += 256) lw[i] = W[i];
    __syncthreads();
    const int row = blockIdx.x * 256 + tid;
    if (row >= N) return;
    float x[64];
    const float4* p = reinterpret_cast<const float4*>(X + (size_t)row * 32);
    #pragma unroll
    for (int q = 0; q < 8; ++q) {
        float4 v = p[q];
        x[q*4+0] = v.x; x[q*4+1] = v.y; x[q*4+2] = v.z; x[q*4+3] = v.w;
    }
    #pragma unroll
    for (int i = 0; i < 32; ++i) x[32+i] = x[i] * x[i];
    const float4* lw4 = reinterpret_cast<const float4*>(lw);
    float4* yo = reinterpret_cast<float4*>(Y + (size_t)row * 32);
    #pragma unroll
    for (int j4 = 0; j4 < 8; ++j4) {
        float4 s = {0.f, 0.f, 0.f, 0.f};
        #pragma unroll
        for (int i = 0; i < 64; ++i) {
            float4 wf = lw4[i * 8 + j4];
            s.x = fmaf(x[i], wf.x, s.x);
            s.y = fmaf(x[i], wf.y, s.y);
            s.z = fmaf(x[i], wf.z, s.z);
            s.w = fmaf(x[i], wf.w, s.w);
        }
        yo[j4] = s;
    }
}

__global__ __launch_bounds__(256) void spmm_kernel(
    const int* __restrict__ rows, const int* __restrict__ cols,
    const float* __restrict__ vals,
    const float* __restrict__ Y, float* __restrict__ acc, int nnz)
{
    const int t = blockIdx.x * 256 + threadIdx.x;
    const int e = t >> 3, c = t & 7;
    if (e >= nnz) return;
    const int r = rows[e], col = cols[e];
    const float v = vals[e];
    const float4 yv = reinterpret_cast<const float4*>(Y + (size_t)col * 32)[c];
    float* a = acc + (size_t)r * 32 + c * 4;
    unsafeAtomicAdd(a + 0, v * yv.x);
    unsafeAtomicAdd(a + 1, v * yv.y);
    unsafeAtomicAdd(a + 2, v * yv.z);
    unsafeAtomicAdd(a + 3, v * yv.w);
}

// ---------------------------------------------------------------------------
// K3: per (graph, level) top-k + pooled gather + conv1d(kernel=stride=64)+relu
// ---------------------------------------------------------------------------
__global__ __launch_bounds__(256) void topk_conv_kernel(
    const float* __restrict__ X0, const float* __restrict__ X1,
    const float* __restrict__ X2,
    const float* __restrict__ acc0, const float* __restrict__ acc1,
    const float* __restrict__ acc2,
    const float* __restrict__ keys0, const float* __restrict__ keys1,
    const float* __restrict__ keys2,
    const float* __restrict__ CW0, const float* __restrict__ CW1,
    const float* __restrict__ CW2,
    float* __restrict__ xfeat)
{
    const int lvl = blockIdx.y;
    const int g   = blockIdx.x;
    int n, k, base; const float* X; const float* acc; const float* keys;
    const float* cw; float scale;
    if (lvl == 0)      { n = 2000; k = KNc; base = 0;             X = X0; acc = acc0; keys = keys0; cw = CW0; scale = 0.5f; }
    else if (lvl == 1) { n = 4000; k = KEc; base = COC*KNc;       X = X1; acc = acc1; keys = keys1; cw = CW1; scale = 1.0f/3.0f; }
    else               { n = 2000; k = KTc; base = COC*(KNc+KEc); X = X2; acc = acc2; keys = keys2; cw = CW2; scale = 0.5f; }

    __shared__ int  hist[2048];
    __shared__ int  smi[256];
    __shared__ u64  cand[CANDMAX];
    __shared__ u64  red[4];
    __shared__ float pooled[KEc][68];
    __shared__ float wt[64][16];
    __shared__ int  sel[KEc];
    __shared__ int  sT, mcur;

    const int tid = threadIdx.x;
    const size_t rowbase = (size_t)g * n;

    for (int i = tid; i < 2048; i += 256) hist[i] = 0;
    if (tid == 0) { sT = -1; mcur = 0; }
    __syncthreads();

    u64 kreg[16];
    #pragma unroll
    for (int i = 0; i < 16; ++i) {
        const int r = i * 256 + tid;
        u64 kk = 0ULL;
        if (r < n) {
            const float kv = keys ? keys[rowbase + r]
                                  : scale * fmaxf(acc[(rowbase + r) * 32 + 31], 0.0f);
            const u32 kb = (kv > 0.0f) ? __float_as_uint(kv) : 0u;
            kk = ((u64)kb << 32) | (u32)(~r);
            if (kb) atomicAdd(&hist[kb >> 20], 1);
        }
        kreg[i] = kk;
    }
    for (int i = tid; i < COC * 64; i += 256) wt[i & 63][i >> 6] = cw[i];
    __syncthreads();

    int lb[8]; int ls = 0;
    #pragma unroll
    for (int i = 0; i < 8; ++i) { lb[i] = hist[tid * 8 + i]; ls += lb[i]; }
    smi[tid] = ls;
    __syncthreads();
    for (int off = 1; off < 256; off <<= 1) {
        int t = (tid >= off) ? smi[tid - off] : 0;
        __syncthreads();
        smi[tid] += t;
        __syncthreads();
    }
    const int total = smi[255];
    const int suf = total - smi[tid];
    if (total >= k && suf < k && suf + ls >= k) {
        int c = suf;
        for (int i = 7; i >= 0; --i) {
            c += lb[i];
            if (c >= k) { sT = tid * 8 + i; break; }
        }
    }
    __syncthreads();

    bool fast = (sT >= 0);
    if (fast) {
        #pragma unroll
        for (int i = 0; i < 16; ++i) {
            const u32 kb = (u32)(kreg[i] >> 32);
            if (kb && (int)(kb >> 20) >= sT) {
                const int pos = atomicAdd(&mcur, 1);
                if (pos < CANDMAX) cand[pos] = kreg[i];
            }
        }
        __syncthreads();
        const int M = mcur;
        if (M <= CANDMAX) {
            for (int i = tid; i < M; i += 256) {
                const u64 e = cand[i];
                int rank = 0;
                for (int j = 0; j < M; ++j) rank += (cand[j] > e) ? 1 : 0;
                if (rank < k) sel[rank] = (int)(~(u32)e);
            }
        } else {
            fast = false;
        }
    }
    __syncthreads();

    if (!fast) {
        for (int it = 0; it < k; ++it) {
            u64 m = 0ULL;
            #pragma unroll
            for (int i = 0; i < 16; ++i) m = kreg[i] > m ? kreg[i] : m;
            #pragma unroll
            for (int off = 32; off > 0; off >>= 1) {
                u64 o = __shfl_xor(m, off, 64);
                m = o > m ? o : m;
            }
            if ((tid & 63) == 0) red[tid >> 6] = m;
            __syncthreads();
            u64 m0 = red[0], m1 = red[1], m2 = red[2], m3 = red[3];
            u64 ma = m0 > m1 ? m0 : m1;
            u64 mb = m2 > m3 ? m2 : m3;
            u64 mm = ma > mb ? ma : mb;
            if (tid == 0) sel[it] = (int)(~(u32)mm);
            #pragma unroll
            for (int i = 0; i < 16; ++i) if (kreg[i] == mm) kreg[i] = 0ULL;
            __syncthreads();
        }
    }

    for (int t = tid; t < k * 32; t += 256) {
        const int r = t >> 5, i = t & 31;
        const size_t row = rowbase + sel[r];
        pooled[r][i]      = X[row * 32 + i];
        pooled[r][32 + i] = scale * fmaxf(acc[row * 32 + i], 0.0f);
    }
    __syncthreads();

    float* xo = xfeat + (size_t)g * MLP_IN + base;
    for (int t = tid; t < k * COC; t += 256) {
        const int r = t >> 4, co = t & 15;
        float s = 0.f;
        #pragma unroll
        for (int j = 0; j < 64; ++j) s = fmaf(pooled[r][j], wt[j][co], s);
        xo[co * k + r] = fmaxf(s, 0.f);
    }
}

// ---------------------------------------------------------------------------
// K4a/K4b: split MLP
// ---------------------------------------------------------------------------
__global__ __launch_bounds__(256) void mlp_stage1(
    const float* __restrict__ xfeat, const float* __restrict__ W1,
    float* __restrict__ hidp)
{
    const int g = blockIdx.x, s = blockIdx.y;
    const int tid = threadIdx.x;
    const int j = tid & 127, half = tid >> 7;

    __shared__ float xs[KCH];
    __shared__ float red[256];
    if (tid < KCH) xs[tid] = xfeat[(size_t)g * MLP_IN + s * KCH + tid];
    __syncthreads();

    const float* w = W1 + (size_t)(s * KCH + half * (KCH/2)) * MLP_H + j;
    const float* xh = xs + half * (KCH/2);
    float a = 0.f;
    #pragma unroll 4
    for (int i = 0; i < KCH/2; ++i)
        a = fmaf(xh[i], w[(size_t)i * MLP_H], a);

    red[tid] = a;
    __syncthreads();
    if (half == 0)
        hidp[((size_t)g * KSLICE + s) * MLP_H + j] = red[j] + red[128 + j];
}

__global__ __launch_bounds__(128) void mlp_stage2(
    const float* __restrict__ hidp, const float* __restrict__ W2,
    float* __restrict__ out)
{
    const int g = blockIdx.x, j = threadIdx.x;
    float h = 0.f;
    #pragma unroll
    for (int s = 0; s < KSLICE; ++s)
        h += hidp[((size_t)g * KSLICE + s) * MLP_H + j];
    h = fmaxf(h, 0.f);
    __shared__ float hid[MLP_H];
    hid[j] = h;
    __syncthreads();
    if (j < 2) {
        float o = 0.f;
        #pragma unroll 8
        for (int t = 0; t < MLP_H; ++t) o = fmaf(hid[t], W2[t * 2 + j], o);
        out[g * 2 + j] = o;
    }
}

// ---------------------------------------------------------------------------
static inline size_t AL16(size_t x) { return (x + 15) & ~(size_t)15; }
static inline int CEILD(int a, int b) { return (a + b - 1) / b; }

extern "C" void kernel_launch(void* const* d_in, const int* in_sizes, int n_in,
                              void* d_out, int out_size, void* d_ws, size_t ws_size,
                              hipStream_t stream)
{
    const int*   L0r = (const int*)d_in[0];
    const int*   L0c = (const int*)d_in[1];
    const float* L0v = (const float*)d_in[2];
    const int*   L1r = (const int*)d_in[3];
    const int*   L1c = (const int*)d_in[4];
    const float* L1v = (const float*)d_in[5];
    const int*   L2r = (const int*)d_in[6];
    const int*   L2c = (const int*)d_in[7];
    const float* L2v = (const float*)d_in[8];
    const int*   D1r = (const int*)d_in[9];    // D1invB1    (N0 x N1)
    const int*   D1c = (const int*)d_in[10];
    const float* D1v = (const float*)d_in[11];
    const int*   D2r = (const int*)d_in[12];   // D2B1TD1inv (N1 x N0)
    const int*   D2c = (const int*)d_in[13];
    const float* D2v = (const float*)d_in[14];
    const int*   B2r = (const int*)d_in[15];   // B2TD2inv   (N2 x N1)
    const int*   B2c = (const int*)d_in[16];
    const float* B2v = (const float*)d_in[17];
    const int*   B3r = (const int*)d_in[18];   // B2D3       (N1 x N2)
    const int*   B3c = (const int*)d_in[19];
    const float* B3v = (const float*)d_in[20];
    const float* X0  = (const float*)d_in[21];
    const float* X1  = (const float*)d_in[22];
    const float* X2  = (const float*)d_in[23];
    const float* W_n2n = (const float*)d_in[24];
    const float* W_n2e = (const float*)d_in[25];
    const float* W_e2e = (const float*)d_in[26];
    const float* W_e2n = (const float*)d_in[27];
    const float* W_e2t = (const float*)d_in[28];
    const float* W_t2e = (const float*)d_in[29];
    const float* W_t2t = (const float*)d_in[30];
    const float* CWn = (const float*)d_in[31];
    const float* CWe = (const float*)d_in[32];
    const float* CWt = (const float*)d_in[33];
    const float* MW1 = (const float*)d_in[34];
    const float* MW2 = (const float*)d_in[35];

    const int nnzL0 = in_sizes[0],  nnzL1 = in_sizes[3],  nnzL2 = in_sizes[6];
    const int nnzD1 = in_sizes[9],  nnzD2 = in_sizes[12];
    const int nnzB2 = in_sizes[15], nnzB3 = in_sizes[18];

    // groups by target acc: g0=acc0{L0,D1}, g1=acc1{D2,L1,B3}, g2=acc2{B2,L2}
    const size_t g0n = (size_t)nnzL0 + nnzD1;
    const size_t g1n = (size_t)nnzD2 + nnzL1 + nnzB3;
    const size_t g2n = (size_t)nnzB2 + nnzL2;
    size_t gmax = g0n; if (g1n > gmax) gmax = g1n; if (g2n > gmax) gmax = g2n;
    size_t pmax = g0n + g2n; if (g1n > pmax) pmax = g1n;   // [g0|g2] coexist (A3)
    const size_t totnnz = g0n + g1n + g2n;

    const size_t need_common =
        AL16((size_t)N0c*32*4) + AL16((size_t)N1c*32*4) + AL16((size_t)N2c*32*4)   // Ya,Yb,Yc
      + AL16((size_t)N0c*32*4) + AL16((size_t)N1c*32*4) + AL16((size_t)N2c*32*4)   // acc0..2
      + AL16((size_t)BG*MLP_IN*4) + AL16((size_t)BG*KSLICE*MLP_H*4)
      + AL16((size_t)N0c*4) + AL16((size_t)N1c*4) + AL16((size_t)N2c*4)            // keys
      + AL16((size_t)3*N1c*4)                                                       // ptrg
      + AL16((size_t)9*256*4) + AL16((size_t)9*256*4);                              // bincnt, gcur
    const size_t need_A3 = need_common + AL16(pmax*8) + AL16(totnnz*8);
    const size_t need_A2 = need_common + AL16(gmax*8) + AL16(gmax*8);

    char* wp = (char*)d_ws;
    #define WALLOC(ty, name, count) \
        ty* name = (ty*)wp; wp += AL16((size_t)(count) * sizeof(ty));

    if (ws_size >= need_A2) {
        const bool a3 = (ws_size >= need_A3);
        WALLOC(float, Ya,    (size_t)N0c * 32)
        WALLOC(float, Yb,    (size_t)N1c * 32)
        WALLOC(float, Yc,    (size_t)N2c * 32)
        WALLOC(float, acc0,  (size_t)N0c * 32)
        WALLOC(float, acc1,  (size_t)N1c * 32)
        WALLOC(float, acc2,  (size_t)N2c * 32)
        WALLOC(float, xfeat, (size_t)BG * MLP_IN)
        WALLOC(float, hidp,  (size_t)BG * KSLICE * MLP_H)
        WALLOC(float, keys0, (size_t)N0c)
        WALLOC(float, keys1, (size_t)N1c)
        WALLOC(float, keys2, (size_t)N2c)
        WALLOC(u64,   pairs, a3 ? pmax : gmax)
        WALLOC(int,   ptrg,  (size_t)3 * N1c)
        WALLOC(int,   bincnt, 9 * 256)
        WALLOC(int,   gcur,   9 * 256)
        WALLOC(u64,   tmpP,  a3 ? totnnz : gmax)

        hipMemsetAsync(bincnt, 0, 2 * 9 * 256 * sizeof(int), stream);  // bincnt+gcur

        // descriptors.  epb = nbins*4 (lambda=4, BDEPTH=8).
        // tout = pairs offset; tin = tmpP offset (absolute in A3).
        const int nb0 = N0c >> BINSHIFT, nb1 = N1c >> BINSHIFT, nb2 = N2c >> BINSHIFT;
        Mat M[7];
        M[0] = { L0r, L0c, L0v, nnzL0, nb0, nb0*4, 0, 0, 0 };                       // g0
        M[1] = { D1r, D1c, D1v, nnzD1, nb0, nb0*4, 1, 0, nnzL0 };
        M[2] = { D2r, D2c, D2v, nnzD2, nb1, nb1*4, 2, 0, 0 };                       // g1
        M[3] = { L1r, L1c, L1v, nnzL1, nb1, nb1*4, 3, 0, nnzD2 };
        M[4] = { B3r, B3c, B3v, nnzB3, nb1, nb1*4, 4, 0, nnzD2 + nnzL1 };
        M[5] = { B2r, B2c, B2v, nnzB2, nb2, nb2*4, 5, 0, 0 };                       // g2
        M[6] = { L2r, L2c, L2v, nnzL2, nb2, nb2*4, 6, 0, nnzB2 };
        if (a3) {
            int cum = 0;
            for (int i = 0; i < 7; ++i) { M[i].tin = cum; cum += M[i].nnz; }
            // pairs layout in A3: [g0 | g2] coexist (merged build), g1 reuses
            M[5].tout += (int)g0n;
            M[6].tout += (int)g0n;
        } else {
            for (int i = 0; i < 7; ++i) M[i].tin = M[i].tout;
        }

        Mats G1; G1.count = 3; G1.m[0] = M[2]; G1.m[1] = M[3]; G1.m[2] = M[4];

        Lifts L_0; L_0.count = 2;
        L_0.X[0]=X0; L_0.W[0]=W_n2n; L_0.Y[0]=Ya; L_0.N[0]=N0c;
        L_0.X[1]=X1; L_0.W[1]=W_e2n; L_0.Y[1]=Yb; L_0.N[1]=N1c;
        L_0.X[2]=X1; L_0.W[2]=W_e2n; L_0.Y[2]=Yb; L_0.N[2]=0;
        Lifts L_1; L_1.count = 3;
        L_1.X[0]=X0; L_1.W[0]=W_n2e; L_1.Y[0]=Ya; L_1.N[0]=N0c;
        L_1.X[1]=X1; L_1.W[1]=W_e2e; L_1.Y[1]=Yb; L_1.N[1]=N1c;
        L_1.X[2]=X2; L_1.W[2]=W_t2e; L_1.Y[2]=Yc; L_1.N[2]=N2c;
        Lifts L_2; L_2.count = 2;
        L_2.X[0]=X1; L_2.W[0]=W_e2t; L_2.Y[0]=Yb; L_2.N[0]=N1c;
        L_2.X[1]=X2; L_2.W[1]=W_t2t; L_2.Y[1]=Yc; L_2.N[1]=N2c;
        L_2.X[2]=X2; L_2.W[2]=W_t2t; L_2.Y[2]=Yc; L_2.N[2]=0;

        const int liftblk = CEILD(N1c, 256);

        if (a3) {
            // one hist + one scatter for ALL 7 matrices
            Mats ALL; ALL.count = 7;
            for (int i = 0; i < 7; ++i) ALL.m[i] = M[i];
            int maxblk = 0;
            for (int i = 0; i < 7; ++i) {
                const int nb = CEILD(M[i].nnz, M[i].epb);
                if (nb > maxblk) maxblk = nb;
            }
            bin_hist_g<<<dim3(maxblk, 7), 256, 0, stream>>>(ALL, bincnt);
            bin_scatter_g<<<dim3(maxblk, 7), 256, 0, stream>>>(ALL, bincnt, gcur, tmpP);

            // merged g0+g2 build: 4 matrices, shared R = N0c == N2c = 128000
            Mats G02; G02.count = 4;
            G02.m[0] = M[0]; G02.m[1] = M[1]; G02.m[2] = M[5]; G02.m[3] = M[6];
            bin_build_g<<<dim3(nb0, 4), 256, 0, stream>>>(G02, bincnt, tmpP, N0c, pairs, ptrg);

            gemm_lift_g<<<dim3(liftblk, 2), 256, 0, stream>>>(L_0);
            spmm_group<2><<<CEILD(N0c * 8, 256), 256, 0, stream>>>(
                ptrg, N0c, pairs, 0, nnzL0, 0, Ya, Yb, Yb, acc0, keys0, 0.5f);

            gemm_lift_g<<<dim3(liftblk, 2), 256, 0, stream>>>(L_2);
            spmm_group<2><<<CEILD(N2c * 8, 256), 256, 0, stream>>>(
                ptrg + (size_t)2 * N0c, N2c, pairs,
                (int)g0n, (int)g0n + nnzB2, 0, Yb, Yc, Yc, acc2, keys2, 0.5f);

            gemm_lift_g<<<dim3(liftblk, 3), 256, 0, stream>>>(L_1);
            bin_build_g<<<dim3(nb1, 3), 256, 0, stream>>>(G1, bincnt, tmpP, N1c, pairs, ptrg);
            spmm_group<3><<<CEILD(N1c * 8, 256), 256, 0, stream>>>(
                ptrg, N1c, pairs, 0, nnzD2, nnzD2 + nnzL1, Ya, Yb, Yc, acc1, keys1, 1.0f/3.0f);
        } else {
            // group-sequential (tmpP/pairs reused per group)
            Mats G0; G0.count = 2; G0.m[0] = M[0]; G0.m[1] = M[1];
            Mats G2; G2.count = 2; G2.m[0] = M[5]; G2.m[1] = M[6];
            #define RUN_GROUP(G, LD, NLIFT, NBINS, NMAT, R, SPMMCALL)                  \
                do {                                                                    \
                    int mb = 0;                                                         \
                    for (int i = 0; i < (G).count; ++i) {                               \
                        const int nb = CEILD((G).m[i].nnz, (G).m[i].epb);               \
                        if (nb > mb) mb = nb;                                           \
                    }                                                                   \
                    bin_hist_g<<<dim3(mb, NMAT), 256, 0, stream>>>((G), bincnt);        \
                    bin_scatter_g<<<dim3(mb, NMAT), 256, 0, stream>>>((G), bincnt,      \
                                                                      gcur, tmpP);      \
                    gemm_lift_g<<<dim3(liftblk, NLIFT), 256, 0, stream>>>(LD);          \
                    bin_build_g<<<dim3(NBINS, NMAT), 256, 0, stream>>>((G), bincnt,     \
                                                                tmpP, (R), pairs, ptrg);\
                    SPMMCALL;                                                           \
                } while (0)

            RUN_GROUP(G0, L_0, 2, nb0, 2, N0c,
                (spmm_group<2><<<CEILD(N0c * 8, 256), 256, 0, stream>>>(
                    ptrg, N0c, pairs, 0, nnzL0, 0, Ya, Yb, Yb, acc0, keys0, 0.5f)));
            RUN_GROUP(G1, L_1, 3, nb1, 3, N1c,
                (spmm_group<3><<<CEILD(N1c * 8, 256), 256, 0, stream>>>(
                    ptrg, N1c, pairs, 0, nnzD2, nnzD2 + nnzL1, Ya, Yb, Yc, acc1, keys1, 1.0f/3.0f)));
            RUN_GROUP(G2, L_2, 2, nb2, 2, N2c,
                (spmm_group<2><<<CEILD(N2c * 8, 256), 256, 0, stream>>>(
                    ptrg, N2c, pairs, 0, nnzB2, 0, Yb, Yc, Yc, acc2, keys2, 0.5f)));
            #undef RUN_GROUP
        }

        topk_conv_kernel<<<dim3(BG, 3), 256, 0, stream>>>(X0, X1, X2, acc0, acc1, acc2,
                                                          keys0, keys1, keys2,
                                                          CWn, CWe, CWt, xfeat);
        mlp_stage1<<<dim3(BG, KSLICE), 256, 0, stream>>>(xfeat, MW1, hidp);
        mlp_stage2<<<BG, MLP_H, 0, stream>>>(hidp, MW2, (float*)d_out);
    } else {
        // =============== tier C: atomic COO path ============================
        WALLOC(float, Y,     (size_t)N1c * 32)
        WALLOC(float, acc0,  (size_t)N0c * 32)
        WALLOC(float, acc1,  (size_t)N1c * 32)
        WALLOC(float, acc2,  (size_t)N2c * 32)
        WALLOC(float, xfeat, (size_t)BG * MLP_IN)
        WALLOC(float, hidp,  (size_t)BG * KSLICE * MLP_H)

        hipMemsetAsync(acc0, 0, (size_t)(N0c + N1c + N2c) * 32 * sizeof(float), stream);
        #define LIFT(Xp, Np, Wp) \
            gemm_lift<<<CEILD((Np), 256), 256, 0, stream>>>((Xp), (Np), (Wp), Y)
        #define SPMM(rp, cp, vp, nz, accp) \
            spmm_kernel<<<CEILD((nz) * 8, 256), 256, 0, stream>>>((rp), (cp), (vp), Y, (accp), (nz))
        LIFT(X0, N0c, W_n2n);  SPMM(L0r, L0c, L0v, nnzL0, acc0);
        LIFT(X0, N0c, W_n2e);  SPMM(D2r, D2c, D2v, nnzD2, acc1);
        LIFT(X1, N1c, W_e2e);  SPMM(L1r, L1c, L1v, nnzL1, acc1);
        LIFT(X1, N1c, W_e2n);  SPMM(D1r, D1c, D1v, nnzD1, acc0);
        LIFT(X1, N1c, W_e2t);  SPMM(B2r, B2c, B2v, nnzB2, acc2);
        LIFT(X2, N2c, W_t2t);  SPMM(L2r, L2c, L2v, nnzL2, acc2);
        LIFT(X2, N2c, W_t2e);  SPMM(B3r, B3c, B3v, nnzB3, acc1);
        #undef LIFT
        #undef SPMM

        topk_conv_kernel<<<dim3(BG, 3), 256, 0, stream>>>(X0, X1, X2, acc0, acc1, acc2,
                                                          nullptr, nullptr, nullptr,
                                                          CWn, CWe, CWt, xfeat);
        mlp_stage1<<<dim3(BG, KSLICE), 256, 0, stream>>>(xfeat, MW1, hidp);
        mlp_stage2<<<BG, MLP_H, 0, stream>>>(hidp, MW2, (float*)d_out);
    }
    #undef WALLOC
}

// Round 20
// 532.451 us; speedup vs baseline: 1.2152x; 1.2152x over previous
//
#include <hip/hip_runtime.h>

// ---------------- problem constants (fixed by reference) ----------------
#define N0c 128000
#define N1c 256000
#define N2c 128000
#define BG  64        // graphs per batch
#define KNc 30
#define KEc 60
#define KTc 30
#define COC 16        // conv out channels
#define MLP_IN 1920   // 16*(30+60+30)
#define MLP_H 128
#define KSLICE 8      // MLP stage-1 k-split
#define KCH (MLP_IN / KSLICE)   // 240

#define BINSHIFT 10           // 1024 rows per bin
#define BINROWS  1024
#define BDEPTH   16           // LDS staging depth per bin (epb=nbins*8, lambda=8)
#define BSTRIDE  17           // padded stride (r16 bank fix)
#define BCAP     12288        // max entries per (matrix,bin) in bin_build
#define CANDMAX  256          // topk radix-select candidate cap

typedef unsigned long long u64;
typedef unsigned int u32;

// 60-bit packed tmp entry: val[63:32] | col[27:10] (18b) | rowlo[9:0]
// pairs entry (spmm input): val[63:32] | col[31:0]

struct Mat {
    const int* r; const int* c; const float* v;
    int nnz, nbins, epb, slot, tin, tout;
};
struct Mats { Mat m[7]; int count; };
struct Lifts {
    const float* X[3]; const float* W[3]; float* Y[3];
    int N[3]; int count;
};

// ---------------------------------------------------------------------------
// K1g: batched fused polynomial lift + dense GEMM (grid.y = lift index)
// ---------------------------------------------------------------------------
__global__ __launch_bounds__(256) void gemm_lift_g(Lifts ld)
{
    const int j = blockIdx.y;          // uniform -> scalar selects
    if (j >= ld.count) return;
    const float* __restrict__ X = ld.X[j];
    const float* __restrict__ W = ld.W[j];
    float* __restrict__ Y = ld.Y[j];
    const int N = ld.N[j];

    __shared__ float lw[2048];            // [64][32]
    const int tid = threadIdx.x;
    for (int i = tid; i < 2048; i += 256) lw[i] = W[i];
    __syncthreads();

    const int row = blockIdx.x * 256 + tid;
    if (row >= N) return;

    float x[64];
    const float4* p = reinterpret_cast<const float4*>(X + (size_t)row * 32);
    #pragma unroll
    for (int q = 0; q < 8; ++q) {
        float4 v = p[q];
        x[q*4+0] = v.x; x[q*4+1] = v.y; x[q*4+2] = v.z; x[q*4+3] = v.w;
    }
    #pragma unroll
    for (int i = 0; i < 32; ++i) x[32+i] = x[i] * x[i];

    const float4* lw4 = reinterpret_cast<const float4*>(lw);
    float4* yo = reinterpret_cast<float4*>(Y + (size_t)row * 32);
    #pragma unroll
    for (int j4 = 0; j4 < 8; ++j4) {
        float4 s = {0.f, 0.f, 0.f, 0.f};
        #pragma unroll
        for (int i = 0; i < 64; ++i) {
            float4 wf = lw4[i * 8 + j4];     // broadcast LDS read
            s.x = fmaf(x[i], wf.x, s.x);
            s.y = fmaf(x[i], wf.y, s.y);
            s.z = fmaf(x[i], wf.z, s.z);
            s.w = fmaf(x[i], wf.w, s.w);
        }
        yo[j4] = s;
    }
}

// ---------------------------------------------------------------------------
// B1: batched per-block LDS histogram over bins (grid.y = matrix)
// ---------------------------------------------------------------------------
__global__ __launch_bounds__(256) void bin_hist_g(Mats ms, int* __restrict__ bincnt)
{
    const int j = blockIdx.y;
    if (j >= ms.count) return;
    const Mat mm = ms.m[j];
    const int base = blockIdx.x * mm.epb;
    if (base >= mm.nnz) return;
    int* bc = bincnt + mm.slot * 256;

    __shared__ int lh[256];
    const int tid = threadIdx.x;
    lh[tid] = 0;
    __syncthreads();
    const int cnt = min(mm.epb, mm.nnz - base);
    for (int i = tid; i < cnt; i += 256)
        atomicAdd(&lh[mm.r[base + i] >> BINSHIFT], 1);
    __syncthreads();
    if (tid < mm.nbins && lh[tid]) atomicAdd(&bc[tid], lh[tid]);
}

// ---------------------------------------------------------------------------
// B2: batched LDS-staged binned scatter -> tmpP (60-bit packed).
// Per-thread flush (r11/r12: concurrent per-bin atomics).  BDEPTH=16/
// BSTRIDE=17/epb=nbins*8: proven r16/r18 config (r19: halving the slice
// doubled flush overhead + write amp -> regressed; occupancy wasn't binding).
// ---------------------------------------------------------------------------
__global__ __launch_bounds__(256) void bin_scatter_g(
    Mats ms, const int* __restrict__ bincnt, int* __restrict__ gcur,
    u64* __restrict__ tmpP)
{
    const int j = blockIdx.y;
    if (j >= ms.count) return;
    const Mat mm = ms.m[j];
    const int blkbase = blockIdx.x * mm.epb;
    if (blkbase >= mm.nnz) return;
    const int* bc = bincnt + mm.slot * 256;
    int* gc = gcur + mm.slot * 256;

    __shared__ u64 bP[256 * BSTRIDE];  // 34 KB (padded)
    __shared__ int lc[256];
    __shared__ int smo[256];           // inclusive scan of bincnt slice
    const int tid = threadIdx.x;
    lc[tid] = 0;
    smo[tid] = (tid < mm.nbins) ? bc[tid] : 0;
    __syncthreads();
    for (int off = 1; off < 256; off <<= 1) {
        int t_ = (tid >= off) ? smo[tid - off] : 0;
        __syncthreads();
        smo[tid] += t_;
        __syncthreads();
    }

    const int cnt = min(mm.epb, mm.nnz - blkbase);
    for (int i = tid; i < cnt; i += 256) {
        const int e = blkbase + i;
        const int r = mm.r[e];
        const u64 pv = ((u64)__float_as_uint(mm.v[e]) << 32)
                     | ((u32)mm.c[e] << 10) | (u32)(r & (BINROWS - 1));
        const int b = r >> BINSHIFT;
        const int p = atomicAdd(&lc[b], 1);
        if (p < BDEPTH) {
            bP[b * BSTRIDE + p] = pv;
        } else {                               // rare spill (~0.3%)
            const int off0 = mm.tin + ((b == 0) ? 0 : smo[b - 1]);
            const int g = off0 + atomicAdd(&gc[b], 1);
            tmpP[g] = pv;
        }
    }
    __syncthreads();

    // per-thread flush: thread tid owns bin tid (concurrent atomics)
    if (tid < mm.nbins) {
        int len = lc[tid]; if (len > BDEPTH) len = BDEPTH;
        if (len) {
            const int off0 = mm.tin + ((tid == 0) ? 0 : smo[tid - 1]);
            const int g = off0 + atomicAdd(&gc[tid], len);
            for (int i = 0; i < len; ++i) tmpP[g + i] = bP[tid * BSTRIDE + i];
        }
    }
}

// ---------------------------------------------------------------------------
// B3: batched bin_build: grid (nbins, nmat).  Counting-sort bin entries of
// matrix j into pairs (val<<32|col), emit per-matrix ptr slice (inclusive
// row ends, absolute into pairs).
// ---------------------------------------------------------------------------
__global__ __launch_bounds__(256) void bin_build_g(
    Mats ms, const int* __restrict__ bincnt,
    const u64* __restrict__ tmpP, int R,
    u64* __restrict__ pairs, int* __restrict__ ptrg)
{
    __shared__ unsigned short rl[BCAP];        // 24 KB
    __shared__ int h[BINROWS];                 // 4 KB
    __shared__ int cur[BINROWS];               // 4 KB
    __shared__ int sm[256];
    const int b = blockIdx.x, j = blockIdx.y, tid = threadIdx.x;
    const Mat mm = ms.m[j];
    const int* bc = bincnt + mm.slot * 256;
    int* ptr = ptrg + (size_t)j * R;

    sm[tid] = (tid < mm.nbins) ? bc[tid] : 0;
    __syncthreads();
    for (int off = 1; off < 256; off <<= 1) {
        int t_ = (tid >= off) ? sm[tid - off] : 0;
        __syncthreads();
        sm[tid] += t_;
        __syncthreads();
    }
    const int pre = (b == 0) ? 0 : sm[b - 1];
    const int base_in  = mm.tin  + pre;
    const int base_out = mm.tout + pre;
    int len = sm[b] - pre;
    if (len > BCAP) len = BCAP;                // never expected
    __syncthreads();

    for (int i = tid; i < BINROWS; i += 256) h[i] = 0;
    __syncthreads();
    for (int i = tid; i < len; i += 256) {
        const int r = (int)(tmpP[base_in + i] & (BINROWS - 1));
        rl[i] = (unsigned short)r;
        atomicAdd(&h[r], 1);
    }
    __syncthreads();

    const int i0 = tid * 4;
    const int a0 = h[i0], a1 = h[i0+1], a2 = h[i0+2], a3 = h[i0+3];
    const int s = a0 + a1 + a2 + a3;
    sm[tid] = s;
    __syncthreads();
    for (int off = 1; off < 256; off <<= 1) {
        int t_ = (tid >= off) ? sm[tid - off] : 0;
        __syncthreads();
        sm[tid] += t_;
        __syncthreads();
    }
    const int run = sm[tid] - s;
    cur[i0]   = run;
    cur[i0+1] = run + a0;
    cur[i0+2] = run + a0 + a1;
    cur[i0+3] = run + a0 + a1 + a2;
    const int rstart = b << BINSHIFT;
    if (rstart + i0     < R) ptr[rstart + i0    ] = base_out + run + a0;
    if (rstart + i0 + 1 < R) ptr[rstart + i0 + 1] = base_out + run + a0 + a1;
    if (rstart + i0 + 2 < R) ptr[rstart + i0 + 2] = base_out + run + a0 + a1 + a2;
    if (rstart + i0 + 3 < R) ptr[rstart + i0 + 3] = base_out + run + a0 + a1 + a2 + a3;
    __syncthreads();

    for (int i = tid; i < len; i += 256) {
        const u64 e8 = tmpP[base_in + i];      // L2-hot second read
        const int r = rl[i];
        const int pos = base_out + atomicAdd(&cur[r], 1);
        pairs[pos] = ((e8 >> 32) << 32) | ((e8 >> 10) & 0x3FFFFu);
    }
}

// ---------------------------------------------------------------------------
// K2: grouped CSR gather SPMM: per row, accumulate over NMAT matrices in
// registers; acc written ONCE; sortpool key fused.
// ---------------------------------------------------------------------------
template<int NMAT>
__global__ __launch_bounds__(256) void spmm_group(
    const int* __restrict__ ptrg, int R,
    const u64* __restrict__ pairs,
    int t0, int t1, int t2,
    const float* __restrict__ Y0, const float* __restrict__ Y1,
    const float* __restrict__ Y2,
    float* __restrict__ acc, float* __restrict__ keyout, float kscale)
{
    const int t = blockIdx.x * 256 + threadIdx.x;
    const int row = t >> 3;
    const int l8  = t & 7;
    if (row >= R) return;

    float4 a = {0.f, 0.f, 0.f, 0.f};
    #pragma unroll
    for (int m = 0; m < NMAT; ++m) {
        const int* pm = ptrg + (size_t)m * R;
        const int toff = (m == 0) ? t0 : (m == 1) ? t1 : t2;
        const float4* Y4 = reinterpret_cast<const float4*>(
            (m == 0) ? Y0 : (m == 1) ? Y1 : Y2);
        const int s = (row == 0) ? toff : pm[row - 1];
        const int e = pm[row];
        for (int base = s; base < e; base += 8) {
            int mm = e - base; if (mm > 8) mm = 8;
            u64 pk = (l8 < mm) ? pairs[base + l8] : 0ULL;
            for (int jj = 0; jj < mm; ++jj) {
                const u64 pj = __shfl(pk, jj, 8);
                const int col   = (int)(u32)(pj & 0xffffffffu);
                const float val = __uint_as_float((u32)(pj >> 32));
                const float4 y = Y4[(size_t)col * 8 + l8];
                a.x = fmaf(val, y.x, a.x); a.y = fmaf(val, y.y, a.y);
                a.z = fmaf(val, y.z, a.z); a.w = fmaf(val, y.w, a.w);
            }
        }
    }
    reinterpret_cast<float4*>(acc)[(size_t)row * 8 + l8] = a;
    if (l8 == 7) keyout[row] = kscale * fmaxf(a.w, 0.0f);
}

// ================= tier C fallback: plain lift + atomic COO SPMM ============
__global__ __launch_bounds__(256) void gemm_lift(
    const float* __restrict__ X, int N, const float* __restrict__ W,
    float* __restrict__ Y)
{
    __shared__ float lw[2048];
    const int tid = threadIdx.x;
    for (int i = tid; i < 2048; i += 256) lw[i] = W[i];
    __syncthreads();
    const int row = blockIdx.x * 256 + tid;
    if (row >= N) return;
    float x[64];
    const float4* p = reinterpret_cast<const float4*>(X + (size_t)row * 32);
    #pragma unroll
    for (int q = 0; q < 8; ++q) {
        float4 v = p[q];
        x[q*4+0] = v.x; x[q*4+1] = v.y; x[q*4+2] = v.z; x[q*4+3] = v.w;
    }
    #pragma unroll
    for (int i = 0; i < 32; ++i) x[32+i] = x[i] * x[i];
    const float4* lw4 = reinterpret_cast<const float4*>(lw);
    float4* yo = reinterpret_cast<float4*>(Y + (size_t)row * 32);
    #pragma unroll
    for (int j4 = 0; j4 < 8; ++j4) {
        float4 s = {0.f, 0.f, 0.f, 0.f};
        #pragma unroll
        for (int i = 0; i < 64; ++i) {
            float4 wf = lw4[i * 8 + j4];
            s.x = fmaf(x[i], wf.x, s.x);
            s.y = fmaf(x[i], wf.y, s.y);
            s.z = fmaf(x[i], wf.z, s.z);
            s.w = fmaf(x[i], wf.w, s.w);
        }
        yo[j4] = s;
    }
}

__global__ __launch_bounds__(256) void spmm_kernel(
    const int* __restrict__ rows, const int* __restrict__ cols,
    const float* __restrict__ vals,
    const float* __restrict__ Y, float* __restrict__ acc, int nnz)
{
    const int t = blockIdx.x * 256 + threadIdx.x;
    const int e = t >> 3, c = t & 7;
    if (e >= nnz) return;
    const int r = rows[e], col = cols[e];
    const float v = vals[e];
    const float4 yv = reinterpret_cast<const float4*>(Y + (size_t)col * 32)[c];
    float* a = acc + (size_t)r * 32 + c * 4;
    unsafeAtomicAdd(a + 0, v * yv.x);
    unsafeAtomicAdd(a + 1, v * yv.y);
    unsafeAtomicAdd(a + 2, v * yv.z);
    unsafeAtomicAdd(a + 3, v * yv.w);
}

// ---------------------------------------------------------------------------
// K3: per (graph, level) top-k + pooled gather + conv1d(kernel=stride=64)+relu
// ---------------------------------------------------------------------------
__global__ __launch_bounds__(256) void topk_conv_kernel(
    const float* __restrict__ X0, const float* __restrict__ X1,
    const float* __restrict__ X2,
    const float* __restrict__ acc0, const float* __restrict__ acc1,
    const float* __restrict__ acc2,
    const float* __restrict__ keys0, const float* __restrict__ keys1,
    const float* __restrict__ keys2,
    const float* __restrict__ CW0, const float* __restrict__ CW1,
    const float* __restrict__ CW2,
    float* __restrict__ xfeat)
{
    const int lvl = blockIdx.y;
    const int g   = blockIdx.x;
    int n, k, base; const float* X; const float* acc; const float* keys;
    const float* cw; float scale;
    if (lvl == 0)      { n = 2000; k = KNc; base = 0;             X = X0; acc = acc0; keys = keys0; cw = CW0; scale = 0.5f; }
    else if (lvl == 1) { n = 4000; k = KEc; base = COC*KNc;       X = X1; acc = acc1; keys = keys1; cw = CW1; scale = 1.0f/3.0f; }
    else               { n = 2000; k = KTc; base = COC*(KNc+KEc); X = X2; acc = acc2; keys = keys2; cw = CW2; scale = 0.5f; }

    __shared__ int  hist[2048];
    __shared__ int  smi[256];
    __shared__ u64  cand[CANDMAX];
    __shared__ u64  red[4];
    __shared__ float pooled[KEc][68];
    __shared__ float wt[64][16];
    __shared__ int  sel[KEc];
    __shared__ int  sT, mcur;

    const int tid = threadIdx.x;
    const size_t rowbase = (size_t)g * n;

    for (int i = tid; i < 2048; i += 256) hist[i] = 0;
    if (tid == 0) { sT = -1; mcur = 0; }
    __syncthreads();

    u64 kreg[16];
    #pragma unroll
    for (int i = 0; i < 16; ++i) {
        const int r = i * 256 + tid;
        u64 kk = 0ULL;
        if (r < n) {
            const float kv = keys ? keys[rowbase + r]
                                  : scale * fmaxf(acc[(rowbase + r) * 32 + 31], 0.0f);
            const u32 kb = (kv > 0.0f) ? __float_as_uint(kv) : 0u;
            kk = ((u64)kb << 32) | (u32)(~r);
            if (kb) atomicAdd(&hist[kb >> 20], 1);
        }
        kreg[i] = kk;
    }
    for (int i = tid; i < COC * 64; i += 256) wt[i & 63][i >> 6] = cw[i];
    __syncthreads();

    int lb[8]; int ls = 0;
    #pragma unroll
    for (int i = 0; i < 8; ++i) { lb[i] = hist[tid * 8 + i]; ls += lb[i]; }
    smi[tid] = ls;
    __syncthreads();
    for (int off = 1; off < 256; off <<= 1) {
        int t = (tid >= off) ? smi[tid - off] : 0;
        __syncthreads();
        smi[tid] += t;
        __syncthreads();
    }
    const int total = smi[255];
    const int suf = total - smi[tid];
    if (total >= k && suf < k && suf + ls >= k) {
        int c = suf;
        for (int i = 7; i >= 0; --i) {
            c += lb[i];
            if (c >= k) { sT = tid * 8 + i; break; }
        }
    }
    __syncthreads();

    bool fast = (sT >= 0);
    if (fast) {
        #pragma unroll
        for (int i = 0; i < 16; ++i) {
            const u32 kb = (u32)(kreg[i] >> 32);
            if (kb && (int)(kb >> 20) >= sT) {
                const int pos = atomicAdd(&mcur, 1);
                if (pos < CANDMAX) cand[pos] = kreg[i];
            }
        }
        __syncthreads();
        const int M = mcur;
        if (M <= CANDMAX) {
            for (int i = tid; i < M; i += 256) {
                const u64 e = cand[i];
                int rank = 0;
                for (int j = 0; j < M; ++j) rank += (cand[j] > e) ? 1 : 0;
                if (rank < k) sel[rank] = (int)(~(u32)e);
            }
        } else {
            fast = false;
        }
    }
    __syncthreads();

    if (!fast) {
        for (int it = 0; it < k; ++it) {
            u64 m = 0ULL;
            #pragma unroll
            for (int i = 0; i < 16; ++i) m = kreg[i] > m ? kreg[i] : m;
            #pragma unroll
            for (int off = 32; off > 0; off >>= 1) {
                u64 o = __shfl_xor(m, off, 64);
                m = o > m ? o : m;
            }
            if ((tid & 63) == 0) red[tid >> 6] = m;
            __syncthreads();
            u64 m0 = red[0], m1 = red[1], m2 = red[2], m3 = red[3];
            u64 ma = m0 > m1 ? m0 : m1;
            u64 mb = m2 > m3 ? m2 : m3;
            u64 mm = ma > mb ? ma : mb;
            if (tid == 0) sel[it] = (int)(~(u32)mm);
            #pragma unroll
            for (int i = 0; i < 16; ++i) if (kreg[i] == mm) kreg[i] = 0ULL;
            __syncthreads();
        }
    }

    for (int t = tid; t < k * 32; t += 256) {
        const int r = t >> 5, i = t & 31;
        const size_t row = rowbase + sel[r];
        pooled[r][i]      = X[row * 32 + i];
        pooled[r][32 + i] = scale * fmaxf(acc[row * 32 + i], 0.0f);
    }
    __syncthreads();

    float* xo = xfeat + (size_t)g * MLP_IN + base;
    for (int t = tid; t < k * COC; t += 256) {
        const int r = t >> 4, co = t & 15;
        float s = 0.f;
        #pragma unroll
        for (int j = 0; j < 64; ++j) s = fmaf(pooled[r][j], wt[j][co], s);
        xo[co * k + r] = fmaxf(s, 0.f);
    }
}

// ---------------------------------------------------------------------------
// K4a/K4b: split MLP
// ---------------------------------------------------------------------------
__global__ __launch_bounds__(256) void mlp_stage1(
    const float* __restrict__ xfeat, const float* __restrict__ W1,
    float* __restrict__ hidp)
{
    const int g = blockIdx.x, s = blockIdx.y;
    const int tid = threadIdx.x;
    const int j = tid & 127, half = tid >> 7;

    __shared__ float xs[KCH];
    __shared__ float red[256];
    if (tid < KCH) xs[tid] = xfeat[(size_t)g * MLP_IN + s * KCH + tid];
    __syncthreads();

    const float* w = W1 + (size_t)(s * KCH + half * (KCH/2)) * MLP_H + j;
    const float* xh = xs + half * (KCH/2);
    float a = 0.f;
    #pragma unroll 4
    for (int i = 0; i < KCH/2; ++i)
        a = fmaf(xh[i], w[(size_t)i * MLP_H], a);

    red[tid] = a;
    __syncthreads();
    if (half == 0)
        hidp[((size_t)g * KSLICE + s) * MLP_H + j] = red[j] + red[128 + j];
}

__global__ __launch_bounds__(128) void mlp_stage2(
    const float* __restrict__ hidp, const float* __restrict__ W2,
    float* __restrict__ out)
{
    const int g = blockIdx.x, j = threadIdx.x;
    float h = 0.f;
    #pragma unroll
    for (int s = 0; s < KSLICE; ++s)
        h += hidp[((size_t)g * KSLICE + s) * MLP_H + j];
    h = fmaxf(h, 0.f);
    __shared__ float hid[MLP_H];
    hid[j] = h;
    __syncthreads();
    if (j < 2) {
        float o = 0.f;
        #pragma unroll 8
        for (int t = 0; t < MLP_H; ++t) o = fmaf(hid[t], W2[t * 2 + j], o);
        out[g * 2 + j] = o;
    }
}

// ---------------------------------------------------------------------------
static inline size_t AL16(size_t x) { return (x + 15) & ~(size_t)15; }
static inline int CEILD(int a, int b) { return (a + b - 1) / b; }

extern "C" void kernel_launch(void* const* d_in, const int* in_sizes, int n_in,
                              void* d_out, int out_size, void* d_ws, size_t ws_size,
                              hipStream_t stream)
{
    const int*   L0r = (const int*)d_in[0];
    const int*   L0c = (const int*)d_in[1];
    const float* L0v = (const float*)d_in[2];
    const int*   L1r = (const int*)d_in[3];
    const int*   L1c = (const int*)d_in[4];
    const float* L1v = (const float*)d_in[5];
    const int*   L2r = (const int*)d_in[6];
    const int*   L2c = (const int*)d_in[7];
    const float* L2v = (const float*)d_in[8];
    const int*   D1r = (const int*)d_in[9];    // D1invB1    (N0 x N1)
    const int*   D1c = (const int*)d_in[10];
    const float* D1v = (const float*)d_in[11];
    const int*   D2r = (const int*)d_in[12];   // D2B1TD1inv (N1 x N0)
    const int*   D2c = (const int*)d_in[13];
    const float* D2v = (const float*)d_in[14];
    const int*   B2r = (const int*)d_in[15];   // B2TD2inv   (N2 x N1)
    const int*   B2c = (const int*)d_in[16];
    const float* B2v = (const float*)d_in[17];
    const int*   B3r = (const int*)d_in[18];   // B2D3       (N1 x N2)
    const int*   B3c = (const int*)d_in[19];
    const float* B3v = (const float*)d_in[20];
    const float* X0  = (const float*)d_in[21];
    const float* X1  = (const float*)d_in[22];
    const float* X2  = (const float*)d_in[23];
    const float* W_n2n = (const float*)d_in[24];
    const float* W_n2e = (const float*)d_in[25];
    const float* W_e2e = (const float*)d_in[26];
    const float* W_e2n = (const float*)d_in[27];
    const float* W_e2t = (const float*)d_in[28];
    const float* W_t2e = (const float*)d_in[29];
    const float* W_t2t = (const float*)d_in[30];
    const float* CWn = (const float*)d_in[31];
    const float* CWe = (const float*)d_in[32];
    const float* CWt = (const float*)d_in[33];
    const float* MW1 = (const float*)d_in[34];
    const float* MW2 = (const float*)d_in[35];

    const int nnzL0 = in_sizes[0],  nnzL1 = in_sizes[3],  nnzL2 = in_sizes[6];
    const int nnzD1 = in_sizes[9],  nnzD2 = in_sizes[12];
    const int nnzB2 = in_sizes[15], nnzB3 = in_sizes[18];

    // groups by target acc: g0=acc0{L0,D1}, g1=acc1{D2,L1,B3}, g2=acc2{B2,L2}
    const size_t g0n = (size_t)nnzL0 + nnzD1;
    const size_t g1n = (size_t)nnzD2 + nnzL1 + nnzB3;
    const size_t g2n = (size_t)nnzB2 + nnzL2;
    size_t gmax = g0n; if (g1n > gmax) gmax = g1n; if (g2n > gmax) gmax = g2n;
    size_t pmax = g0n + g2n; if (g1n > pmax) pmax = g1n;   // [g0|g2] coexist (A3)
    const size_t totnnz = g0n + g1n + g2n;

    const size_t need_common =
        AL16((size_t)N0c*32*4) + AL16((size_t)N1c*32*4) + AL16((size_t)N2c*32*4)   // Ya,Yb,Yc
      + AL16((size_t)N0c*32*4) + AL16((size_t)N1c*32*4) + AL16((size_t)N2c*32*4)   // acc0..2
      + AL16((size_t)BG*MLP_IN*4) + AL16((size_t)BG*KSLICE*MLP_H*4)
      + AL16((size_t)N0c*4) + AL16((size_t)N1c*4) + AL16((size_t)N2c*4)            // keys
      + AL16((size_t)3*N1c*4)                                                       // ptrg
      + AL16((size_t)9*256*4) + AL16((size_t)9*256*4);                              // bincnt, gcur
    const size_t need_A3 = need_common + AL16(pmax*8) + AL16(totnnz*8);
    const size_t need_A2 = need_common + AL16(gmax*8) + AL16(gmax*8);

    char* wp = (char*)d_ws;
    #define WALLOC(ty, name, count) \
        ty* name = (ty*)wp; wp += AL16((size_t)(count) * sizeof(ty));

    if (ws_size >= need_A2) {
        const bool a3 = (ws_size >= need_A3);
        WALLOC(float, Ya,    (size_t)N0c * 32)
        WALLOC(float, Yb,    (size_t)N1c * 32)
        WALLOC(float, Yc,    (size_t)N2c * 32)
        WALLOC(float, acc0,  (size_t)N0c * 32)
        WALLOC(float, acc1,  (size_t)N1c * 32)
        WALLOC(float, acc2,  (size_t)N2c * 32)
        WALLOC(float, xfeat, (size_t)BG * MLP_IN)
        WALLOC(float, hidp,  (size_t)BG * KSLICE * MLP_H)
        WALLOC(float, keys0, (size_t)N0c)
        WALLOC(float, keys1, (size_t)N1c)
        WALLOC(float, keys2, (size_t)N2c)
        WALLOC(u64,   pairs, a3 ? pmax : gmax)
        WALLOC(int,   ptrg,  (size_t)3 * N1c)
        WALLOC(int,   bincnt, 9 * 256)
        WALLOC(int,   gcur,   9 * 256)
        WALLOC(u64,   tmpP,  a3 ? totnnz : gmax)

        hipMemsetAsync(bincnt, 0, 2 * 9 * 256 * sizeof(int), stream);  // bincnt+gcur

        // descriptors.  epb = nbins*8 (lambda=8, BDEPTH=16 — proven config).
        // tout = pairs offset; tin = tmpP offset (absolute in A3).
        const int nb0 = N0c >> BINSHIFT, nb1 = N1c >> BINSHIFT, nb2 = N2c >> BINSHIFT;
        Mat M[7];
        M[0] = { L0r, L0c, L0v, nnzL0, nb0, nb0*8, 0, 0, 0 };                       // g0
        M[1] = { D1r, D1c, D1v, nnzD1, nb0, nb0*8, 1, 0, nnzL0 };
        M[2] = { D2r, D2c, D2v, nnzD2, nb1, nb1*8, 2, 0, 0 };                       // g1
        M[3] = { L1r, L1c, L1v, nnzL1, nb1, nb1*8, 3, 0, nnzD2 };
        M[4] = { B3r, B3c, B3v, nnzB3, nb1, nb1*8, 4, 0, nnzD2 + nnzL1 };
        M[5] = { B2r, B2c, B2v, nnzB2, nb2, nb2*8, 5, 0, 0 };                       // g2
        M[6] = { L2r, L2c, L2v, nnzL2, nb2, nb2*8, 6, 0, nnzB2 };
        if (a3) {
            int cum = 0;
            for (int i = 0; i < 7; ++i) { M[i].tin = cum; cum += M[i].nnz; }
            // pairs layout in A3: [g0 | g2] coexist (merged build), g1 reuses
            M[5].tout += (int)g0n;
            M[6].tout += (int)g0n;
        } else {
            for (int i = 0; i < 7; ++i) M[i].tin = M[i].tout;
        }

        Mats G1; G1.count = 3; G1.m[0] = M[2]; G1.m[1] = M[3]; G1.m[2] = M[4];

        Lifts L_0; L_0.count = 2;
        L_0.X[0]=X0; L_0.W[0]=W_n2n; L_0.Y[0]=Ya; L_0.N[0]=N0c;
        L_0.X[1]=X1; L_0.W[1]=W_e2n; L_0.Y[1]=Yb; L_0.N[1]=N1c;
        L_0.X[2]=X1; L_0.W[2]=W_e2n; L_0.Y[2]=Yb; L_0.N[2]=0;
        Lifts L_1; L_1.count = 3;
        L_1.X[0]=X0; L_1.W[0]=W_n2e; L_1.Y[0]=Ya; L_1.N[0]=N0c;
        L_1.X[1]=X1; L_1.W[1]=W_e2e; L_1.Y[1]=Yb; L_1.N[1]=N1c;
        L_1.X[2]=X2; L_1.W[2]=W_t2e; L_1.Y[2]=Yc; L_1.N[2]=N2c;
        Lifts L_2; L_2.count = 2;
        L_2.X[0]=X1; L_2.W[0]=W_e2t; L_2.Y[0]=Yb; L_2.N[0]=N1c;
        L_2.X[1]=X2; L_2.W[1]=W_t2t; L_2.Y[1]=Yc; L_2.N[1]=N2c;
        L_2.X[2]=X2; L_2.W[2]=W_t2t; L_2.Y[2]=Yc; L_2.N[2]=0;

        const int liftblk = CEILD(N1c, 256);

        if (a3) {
            // one hist + one scatter for ALL 7 matrices
            Mats ALL; ALL.count = 7;
            for (int i = 0; i < 7; ++i) ALL.m[i] = M[i];
            int maxblk = 0;
            for (int i = 0; i < 7; ++i) {
                const int nb = CEILD(M[i].nnz, M[i].epb);
                if (nb > maxblk) maxblk = nb;
            }
            bin_hist_g<<<dim3(maxblk, 7), 256, 0, stream>>>(ALL, bincnt);
            bin_scatter_g<<<dim3(maxblk, 7), 256, 0, stream>>>(ALL, bincnt, gcur, tmpP);

            // merged g0+g2 build: 4 matrices, shared R = N0c == N2c = 128000
            Mats G02; G02.count = 4;
            G02.m[0] = M[0]; G02.m[1] = M[1]; G02.m[2] = M[5]; G02.m[3] = M[6];
            bin_build_g<<<dim3(nb0, 4), 256, 0, stream>>>(G02, bincnt, tmpP, N0c, pairs, ptrg);

            gemm_lift_g<<<dim3(liftblk, 2), 256, 0, stream>>>(L_0);
            spmm_group<2><<<CEILD(N0c * 8, 256), 256, 0, stream>>>(
                ptrg, N0c, pairs, 0, nnzL0, 0, Ya, Yb, Yb, acc0, keys0, 0.5f);

            gemm_lift_g<<<dim3(liftblk, 2), 256, 0, stream>>>(L_2);
            spmm_group<2><<<CEILD(N2c * 8, 256), 256, 0, stream>>>(
                ptrg + (size_t)2 * N0c, N2c, pairs,
                (int)g0n, (int)g0n + nnzB2, 0, Yb, Yc, Yc, acc2, keys2, 0.5f);

            gemm_lift_g<<<dim3(liftblk, 3), 256, 0, stream>>>(L_1);
            bin_build_g<<<dim3(nb1, 3), 256, 0, stream>>>(G1, bincnt, tmpP, N1c, pairs, ptrg);
            spmm_group<3><<<CEILD(N1c * 8, 256), 256, 0, stream>>>(
                ptrg, N1c, pairs, 0, nnzD2, nnzD2 + nnzL1, Ya, Yb, Yc, acc1, keys1, 1.0f/3.0f);
        } else {
            // group-sequential (tmpP/pairs reused per group)
            Mats G0; G0.count = 2; G0.m[0] = M[0]; G0.m[1] = M[1];
            Mats G2; G2.count = 2; G2.m[0] = M[5]; G2.m[1] = M[6];
            #define RUN_GROUP(G, LD, NLIFT, NBINS, NMAT, R, SPMMCALL)                  \
                do {                                                                    \
                    int mb = 0;                                                         \
                    for (int i = 0; i < (G).count; ++i) {                               \
                        const int nb = CEILD((G).m[i].nnz, (G).m[i].epb);               \
                        if (nb > mb) mb = nb;                                           \
                    }                                                                   \
                    bin_hist_g<<<dim3(mb, NMAT), 256, 0, stream>>>((G), bincnt);        \
                    bin_scatter_g<<<dim3(mb, NMAT), 256, 0, stream>>>((G), bincnt,      \
                                                                      gcur, tmpP);      \
                    gemm_lift_g<<<dim3(liftblk, NLIFT), 256, 0, stream>>>(LD);          \
                    bin_build_g<<<dim3(NBINS, NMAT), 256, 0, stream>>>((G), bincnt,     \
                                                                tmpP, (R), pairs, ptrg);\
                    SPMMCALL;                                                           \
                } while (0)

            RUN_GROUP(G0, L_0, 2, nb0, 2, N0c,
                (spmm_group<2><<<CEILD(N0c * 8, 256), 256, 0, stream>>>(
                    ptrg, N0c, pairs, 0, nnzL0, 0, Ya, Yb, Yb, acc0, keys0, 0.5f)));
            RUN_GROUP(G1, L_1, 3, nb1, 3, N1c,
                (spmm_group<3><<<CEILD(N1c * 8, 256), 256, 0, stream>>>(
                    ptrg, N1c, pairs, 0, nnzD2, nnzD2 + nnzL1, Ya, Yb, Yc, acc1, keys1, 1.0f/3.0f)));
            RUN_GROUP(G2, L_2, 2, nb2, 2, N2c,
                (spmm_group<2><<<CEILD(N2c * 8, 256), 256, 0, stream>>>(
                    ptrg, N2c, pairs, 0, nnzB2, 0, Yb, Yc, Yc, acc2, keys2, 0.5f)));
            #undef RUN_GROUP
        }

        topk_conv_kernel<<<dim3(BG, 3), 256, 0, stream>>>(X0, X1, X2, acc0, acc1, acc2,
                                                          keys0, keys1, keys2,
                                                          CWn, CWe, CWt, xfeat);
        mlp_stage1<<<dim3(BG, KSLICE), 256, 0, stream>>>(xfeat, MW1, hidp);
        mlp_stage2<<<BG, MLP_H, 0, stream>>>(hidp, MW2, (float*)d_out);
    } else {
        // =============== tier C: atomic COO path ============================
        WALLOC(float, Y,     (size_t)N1c * 32)
        WALLOC(float, acc0,  (size_t)N0c * 32)
        WALLOC(float, acc1,  (size_t)N1c * 32)
        WALLOC(float, acc2,  (size_t)N2c * 32)
        WALLOC(float, xfeat, (size_t)BG * MLP_IN)
        WALLOC(float, hidp,  (size_t)BG * KSLICE * MLP_H)

        hipMemsetAsync(acc0, 0, (size_t)(N0c + N1c + N2c) * 32 * sizeof(float), stream);
        #define LIFT(Xp, Np, Wp) \
            gemm_lift<<<CEILD((Np), 256), 256, 0, stream>>>((Xp), (Np), (Wp), Y)
        #define SPMM(rp, cp, vp, nz, accp) \
            spmm_kernel<<<CEILD((nz) * 8, 256), 256, 0, stream>>>((rp), (cp), (vp), Y, (accp), (nz))
        LIFT(X0, N0c, W_n2n);  SPMM(L0r, L0c, L0v, nnzL0, acc0);
        LIFT(X0, N0c, W_n2e);  SPMM(D2r, D2c, D2v, nnzD2, acc1);
        LIFT(X1, N1c, W_e2e);  SPMM(L1r, L1c, L1v, nnzL1, acc1);
        LIFT(X1, N1c, W_e2n);  SPMM(D1r, D1c, D1v, nnzD1, acc0);
        LIFT(X1, N1c, W_e2t);  SPMM(B2r, B2c, B2v, nnzB2, acc2);
        LIFT(X2, N2c, W_t2t);  SPMM(L2r, L2c, L2v, nnzL2, acc2);
        LIFT(X2, N2c, W_t2e);  SPMM(B3r, B3c, B3v, nnzB3, acc1);
        #undef LIFT
        #undef SPMM

        topk_conv_kernel<<<dim3(BG, 3), 256, 0, stream>>>(X0, X1, X2, acc0, acc1, acc2,
                                                          nullptr, nullptr, nullptr,
                                                          CWn, CWe, CWt, xfeat);
        mlp_stage1<<<dim3(BG, KSLICE), 256, 0, stream>>>(xfeat, MW1, hidp);
        mlp_stage2<<<BG, MLP_H, 0, stream>>>(hidp, MW2, (float*)d_out);
    }
    #undef WALLOC
}